// Round 1
// baseline (245.026 us; speedup 1.0000x reference)
//
#include <hip/hip_runtime.h>

typedef unsigned short u16;
typedef __bf16 bf16x8 __attribute__((ext_vector_type(8)));
typedef float f32x4 __attribute__((ext_vector_type(4)));

#define D_MODEL 1024
#define NH 16
#define DKD 64
#define BB 2
#define SS 2048
#define LDSK 72   // padded LDS row stride (elems) for attention tiles: 144B, 16B-aligned

__device__ __forceinline__ u16 f2bf(float f) {
  union { float f; unsigned u; } x; x.f = f;
  unsigned r = x.u + 0x7fffu + ((x.u >> 16) & 1u);
  return (u16)(r >> 16);
}

__device__ __forceinline__ void gld16(const u16* g, u16* l) {
  __builtin_amdgcn_global_load_lds((__attribute__((address_space(1))) void*)(g),
                                   (__attribute__((address_space(3))) void*)(l),
                                   16, 0, 0);
}

// ---------------- prep: fp32 -> bf16 activation convert ----------------
extern "C" __global__ void __launch_bounds__(256) kprep_conv(
    const float* __restrict__ q, const float* __restrict__ k, const float* __restrict__ v,
    u16* __restrict__ xq, u16* __restrict__ xk, u16* __restrict__ xv)
{
  int z = blockIdx.y;
  const float* s = z == 0 ? q : (z == 1 ? k : v);
  u16* d = z == 0 ? xq : (z == 1 ? xk : xv);
  int i = (blockIdx.x * 256 + threadIdx.x) * 4;
  float4 val = *(const float4*)(s + i);
  ushort4 o;
  o.x = f2bf(val.x); o.y = f2bf(val.y); o.z = f2bf(val.z); o.w = f2bf(val.w);
  *(ushort4*)(d + i) = o;
}

// ---------------- prep: weight transpose + bf16 convert ----------------
extern "C" __global__ void __launch_bounds__(256) kprep_wt(
    const float* __restrict__ w0, const float* __restrict__ w1,
    const float* __restrict__ w2, const float* __restrict__ w3,
    u16* __restrict__ o0, u16* __restrict__ o1, u16* __restrict__ o2, u16* __restrict__ o3)
{
  const float* src; u16* dst;
  switch (blockIdx.z) {
    case 0: src = w0; dst = o0; break;
    case 1: src = w1; dst = o1; break;
    case 2: src = w2; dst = o2; break;
    default: src = w3; dst = o3; break;
  }
  __shared__ float t[32][33];
  int n0 = blockIdx.x * 32, k0 = blockIdx.y * 32;
  int tx = threadIdx.x & 31, ty = threadIdx.x >> 5;
  #pragma unroll
  for (int i = 0; i < 32; i += 8)
    t[ty + i][tx] = src[(k0 + ty + i) * D_MODEL + n0 + tx];
  __syncthreads();
  #pragma unroll
  for (int i = 0; i < 32; i += 8)
    dst[(size_t)(n0 + ty + i) * D_MODEL + k0 + tx] = f2bf(t[tx][ty + i]);
}

// ---------------- prep: log(weights + 1e-20) ----------------
extern "C" __global__ void __launch_bounds__(256) klw(
    const float* __restrict__ w, float* __restrict__ lw)
{
  int i = blockIdx.x * 256 + threadIdx.x;
  if (i < BB * SS) lw[i] = logf(w[i] + 1e-20f);
}

// ---------------- shared GEMM core: C(128x128) = A(128xK) * Bt(128xK)^T ----------------
// A row-major MxK bf16 (ld=1024), Bt row-major NxK bf16 (ld=1024)
__device__ __forceinline__ void gemm_tile(const u16* __restrict__ Ag, const u16* __restrict__ Bg,
                                          u16* As, u16* Bs, f32x4 acc[4][4], int tid)
{
  int lane = tid & 63;
  int lr = lane & 15, lg = lane >> 4;
  int w = tid >> 6, wr = w >> 1, wc = w & 1;
  for (int k0 = 0; k0 < D_MODEL; k0 += 32) {
    #pragma unroll
    for (int c = 0; c < 2; ++c) {
      int idx = tid + c * 256;               // 512 chunks of 16B for each tile
      int row = idx >> 2, col = (idx & 3) * 8;
      gld16(Ag + row * D_MODEL + k0 + col, As + idx * 8);
      gld16(Bg + row * D_MODEL + k0 + col, Bs + idx * 8);
    }
    __syncthreads();
    bf16x8 af[4], bfr[4];
    #pragma unroll
    for (int mi = 0; mi < 4; ++mi)
      af[mi] = *(const bf16x8*)(As + (wr * 64 + mi * 16 + lr) * 32 + lg * 8);
    #pragma unroll
    for (int nj = 0; nj < 4; ++nj)
      bfr[nj] = *(const bf16x8*)(Bs + (wc * 64 + nj * 16 + lr) * 32 + lg * 8);
    #pragma unroll
    for (int mi = 0; mi < 4; ++mi)
      #pragma unroll
      for (int nj = 0; nj < 4; ++nj)
        acc[mi][nj] = __builtin_amdgcn_mfma_f32_16x16x32_bf16(af[mi], bfr[nj], acc[mi][nj], 0, 0, 0);
    __syncthreads();
  }
}

// ---------------- fused QKV projection ----------------
extern "C" __global__ void __launch_bounds__(256) kgemm_qkv(
    const u16* __restrict__ xq, const u16* __restrict__ xk, const u16* __restrict__ xv,
    const u16* __restrict__ wqt, const u16* __restrict__ wkt, const u16* __restrict__ wvt,
    const float* __restrict__ bq, const float* __restrict__ bk, const float* __restrict__ bv,
    u16* __restrict__ Qb, u16* __restrict__ Kb, u16* __restrict__ Vb)
{
  __shared__ u16 As[128 * 32], Bs[128 * 32];
  int z = blockIdx.z;
  const u16* X  = z == 0 ? xq : (z == 1 ? xk : xv);
  const u16* Wt = z == 0 ? wqt : (z == 1 ? wkt : wvt);
  const float* bias = z == 0 ? bq : (z == 1 ? bk : bv);
  u16* dst = z == 0 ? Qb : (z == 1 ? Kb : Vb);
  int tid = threadIdx.x;
  f32x4 zero = {0.f, 0.f, 0.f, 0.f};
  f32x4 acc[4][4];
  #pragma unroll
  for (int i = 0; i < 4; ++i)
    #pragma unroll
    for (int j = 0; j < 4; ++j) acc[i][j] = zero;
  int m0 = blockIdx.y * 128, n0 = blockIdx.x * 128;
  gemm_tile(X + (size_t)m0 * D_MODEL, Wt + (size_t)n0 * D_MODEL, As, Bs, acc, tid);
  int lane = tid & 63, lr = lane & 15, lg = lane >> 4;
  int w = tid >> 6, wr = w >> 1, wc = w & 1;
  #pragma unroll
  for (int mi = 0; mi < 4; ++mi)
    #pragma unroll
    for (int nj = 0; nj < 4; ++nj) {
      int n = n0 + wc * 64 + nj * 16 + lr;
      float bs = bias[n];
      int h = n >> 6, dk = n & 63;
      #pragma unroll
      for (int j = 0; j < 4; ++j) {
        int m = m0 + wr * 64 + mi * 16 + lg * 4 + j;
        int b = m >> 11, s = m & 2047;
        dst[(((size_t)(b * NH + h)) * SS + s) * DKD + dk] = f2bf(acc[mi][nj][j] + bs);
      }
    }
}

// ---------------- output projection ----------------
extern "C" __global__ void __launch_bounds__(256) kgemm_o(
    const u16* __restrict__ AO, const u16* __restrict__ wot,
    const float* __restrict__ bo, float* __restrict__ out)
{
  __shared__ u16 As[128 * 32], Bs[128 * 32];
  int tid = threadIdx.x;
  f32x4 zero = {0.f, 0.f, 0.f, 0.f};
  f32x4 acc[4][4];
  #pragma unroll
  for (int i = 0; i < 4; ++i)
    #pragma unroll
    for (int j = 0; j < 4; ++j) acc[i][j] = zero;
  int m0 = blockIdx.y * 128, n0 = blockIdx.x * 128;
  gemm_tile(AO + (size_t)m0 * D_MODEL, wot + (size_t)n0 * D_MODEL, As, Bs, acc, tid);
  int lane = tid & 63, lr = lane & 15, lg = lane >> 4;
  int w = tid >> 6, wr = w >> 1, wc = w & 1;
  #pragma unroll
  for (int mi = 0; mi < 4; ++mi)
    #pragma unroll
    for (int nj = 0; nj < 4; ++nj) {
      int n = n0 + wc * 64 + nj * 16 + lr;
      float bs = bo[n];
      #pragma unroll
      for (int j = 0; j < 4; ++j) {
        int m = m0 + wr * 64 + mi * 16 + lg * 4 + j;
        out[(size_t)m * D_MODEL + n] = acc[mi][nj][j] + bs;
      }
    }
}

// ---------------- flash attention ----------------
// Q,K,V: (B,H,S,64) bf16. lw: (B,S) f32. AO: (B,S,1024) bf16.
extern "C" __global__ void __launch_bounds__(256) kattn(
    const u16* __restrict__ Qb, const u16* __restrict__ Kb, const u16* __restrict__ Vb,
    const float* __restrict__ lw, u16* __restrict__ AO)
{
  __shared__ u16 Ks[64 * LDSK];
  __shared__ u16 Vt[64 * LDSK];
  __shared__ u16 Ps[4][32 * LDSK];
  int tid = threadIdx.x, lane = tid & 63, w = tid >> 6;
  int lr = lane & 15, lg = lane >> 4;
  int bh = blockIdx.y, b = bh >> 4, h = bh & 15;
  int q0 = blockIdx.x * 128;

  const u16* Qg = Qb + ((size_t)bh * SS + q0 + w * 32) * DKD;
  const u16* Kg = Kb + (size_t)bh * SS * DKD;
  const u16* Vg = Vb + (size_t)bh * SS * DKD;
  const float* lwb = lw + b * SS;

  bf16x8 qf[2][2];
  #pragma unroll
  for (int mi = 0; mi < 2; ++mi)
    #pragma unroll
    for (int ki = 0; ki < 2; ++ki)
      qf[mi][ki] = *(const bf16x8*)(Qg + (mi * 16 + lr) * DKD + ki * 32 + lg * 8);

  f32x4 zero = {0.f, 0.f, 0.f, 0.f};
  float mrun[2][4], lrun[2][4];
  f32x4 acco[2][4];
  #pragma unroll
  for (int mi = 0; mi < 2; ++mi)
    #pragma unroll
    for (int j = 0; j < 4; ++j) { mrun[mi][j] = -1e30f; lrun[mi][j] = 0.f; }
  #pragma unroll
  for (int mi = 0; mi < 2; ++mi)
    #pragma unroll
    for (int dn = 0; dn < 4; ++dn) acco[mi][dn] = zero;

  for (int kv0 = 0; kv0 < SS; kv0 += 64) {
    __syncthreads();
    // stage K tile [64 kv][64 dk] -> Ks padded
    #pragma unroll
    for (int c = 0; c < 2; ++c) {
      int idx = tid + c * 256;
      int row = idx >> 3, col = (idx & 7) * 8;
      *(bf16x8*)&Ks[row * LDSK + col] = *(const bf16x8*)(Kg + (size_t)(kv0 + row) * DKD + col);
    }
    // stage V transposed: Vt[dk][kv]
    #pragma unroll
    for (int g = 0; g < 2; ++g) {
      int kvl = (w * 2 + g) * 8;
      union { bf16x8 v; u16 s[8]; } tmp;
      #pragma unroll
      for (int j = 0; j < 8; ++j)
        tmp.s[j] = Vg[(size_t)(kv0 + kvl + j) * DKD + lane];
      *(bf16x8*)&Vt[lane * LDSK + kvl] = tmp.v;
    }
    __syncthreads();

    // scores: S = Q * K^T   (per wave: 32 q rows x 64 kv)
    f32x4 sc[2][4];
    #pragma unroll
    for (int mi = 0; mi < 2; ++mi)
      #pragma unroll
      for (int nj = 0; nj < 4; ++nj) sc[mi][nj] = zero;
    #pragma unroll
    for (int ki = 0; ki < 2; ++ki) {
      bf16x8 kf[4];
      #pragma unroll
      for (int nj = 0; nj < 4; ++nj)
        kf[nj] = *(const bf16x8*)&Ks[(nj * 16 + lr) * LDSK + ki * 32 + lg * 8];
      #pragma unroll
      for (int mi = 0; mi < 2; ++mi)
        #pragma unroll
        for (int nj = 0; nj < 4; ++nj)
          sc[mi][nj] = __builtin_amdgcn_mfma_f32_16x16x32_bf16(qf[mi][ki], kf[nj], sc[mi][nj], 0, 0, 0);
    }
    float lwv[4];
    #pragma unroll
    for (int nj = 0; nj < 4; ++nj) lwv[nj] = lwb[kv0 + nj * 16 + lr];

    // online softmax (rows spread over 16 lanes with same lane>>4)
    #pragma unroll
    for (int mi = 0; mi < 2; ++mi) {
      #pragma unroll
      for (int j = 0; j < 4; ++j) {
        float s0 = sc[mi][0][j] * 0.125f + lwv[0];
        float s1 = sc[mi][1][j] * 0.125f + lwv[1];
        float s2 = sc[mi][2][j] * 0.125f + lwv[2];
        float s3 = sc[mi][3][j] * 0.125f + lwv[3];
        float mx = fmaxf(fmaxf(s0, s1), fmaxf(s2, s3));
        #pragma unroll
        for (int d = 1; d < 16; d <<= 1) mx = fmaxf(mx, __shfl_xor(mx, d));
        float mnew = fmaxf(mrun[mi][j], mx);
        float scal = exp2f((mrun[mi][j] - mnew) * 1.44269504f);
        float p0 = exp2f((s0 - mnew) * 1.44269504f);
        float p1 = exp2f((s1 - mnew) * 1.44269504f);
        float p2 = exp2f((s2 - mnew) * 1.44269504f);
        float p3 = exp2f((s3 - mnew) * 1.44269504f);
        int rrow = (mi * 16 + lg * 4 + j) * LDSK;
        Ps[w][rrow +  0 + lr] = f2bf(p0);
        Ps[w][rrow + 16 + lr] = f2bf(p1);
        Ps[w][rrow + 32 + lr] = f2bf(p2);
        Ps[w][rrow + 48 + lr] = f2bf(p3);
        float ps = (p0 + p1) + (p2 + p3);
        #pragma unroll
        for (int d = 1; d < 16; d <<= 1) ps += __shfl_xor(ps, d);
        lrun[mi][j] = lrun[mi][j] * scal + ps;
        mrun[mi][j] = mnew;
        #pragma unroll
        for (int dn = 0; dn < 4; ++dn) acco[mi][dn][j] *= scal;
      }
    }
    // PV: O += P * V  (P wave-private in LDS; same-wave DS ordering, no barrier needed)
    #pragma unroll
    for (int kk = 0; kk < 2; ++kk) {
      bf16x8 vf[4];
      #pragma unroll
      for (int dn = 0; dn < 4; ++dn)
        vf[dn] = *(const bf16x8*)&Vt[(dn * 16 + lr) * LDSK + kk * 32 + lg * 8];
      #pragma unroll
      for (int mi = 0; mi < 2; ++mi) {
        bf16x8 pf = *(const bf16x8*)&Ps[w][(mi * 16 + lr) * LDSK + kk * 32 + lg * 8];
        #pragma unroll
        for (int dn = 0; dn < 4; ++dn)
          acco[mi][dn] = __builtin_amdgcn_mfma_f32_16x16x32_bf16(pf, vf[dn], acco[mi][dn], 0, 0, 0);
      }
    }
  }
  // epilogue: normalize and write AO (B,S,1024) bf16
  #pragma unroll
  for (int mi = 0; mi < 2; ++mi)
    #pragma unroll
    for (int j = 0; j < 4; ++j) {
      float inv = 1.0f / lrun[mi][j];
      int s = q0 + w * 32 + mi * 16 + lg * 4 + j;
      size_t base = ((size_t)b * SS + s) * D_MODEL + h * DKD;
      #pragma unroll
      for (int dn = 0; dn < 4; ++dn)
        AO[base + dn * 16 + lr] = f2bf(acco[mi][dn][j] * inv);
    }
}

extern "C" void kernel_launch(void* const* d_in, const int* in_sizes, int n_in,
                              void* d_out, int out_size, void* d_ws, size_t ws_size,
                              hipStream_t stream) {
  const float* query = (const float*)d_in[0];
  const float* key_  = (const float*)d_in[1];
  const float* value = (const float*)d_in[2];
  const float* wts   = (const float*)d_in[3];
  const float* wq = (const float*)d_in[4];
  const float* bq = (const float*)d_in[5];
  const float* wk = (const float*)d_in[6];
  const float* bk = (const float*)d_in[7];
  const float* wv = (const float*)d_in[8];
  const float* bv = (const float*)d_in[9];
  const float* wo = (const float*)d_in[10];
  const float* bo = (const float*)d_in[11];
  float* out = (float*)d_out;

  char* ws = (char*)d_ws;
  const size_t MB = 1024 * 1024;
  u16* Xq  = (u16*)(ws + 0 * MB);
  u16* Xk  = (u16*)(ws + 8 * MB);
  u16* Xv  = (u16*)(ws + 16 * MB);
  u16* WqT = (u16*)(ws + 24 * MB);
  u16* WkT = (u16*)(ws + 26 * MB);
  u16* WvT = (u16*)(ws + 28 * MB);
  u16* WoT = (u16*)(ws + 30 * MB);
  u16* Qb  = (u16*)(ws + 32 * MB);
  u16* Kb  = (u16*)(ws + 40 * MB);
  u16* Vb  = (u16*)(ws + 48 * MB);
  u16* AO  = (u16*)(ws + 56 * MB);
  float* lwbuf = (float*)(ws + 64 * MB);

  kprep_conv<<<dim3(4096, 3), 256, 0, stream>>>(query, key_, value, Xq, Xk, Xv);
  kprep_wt<<<dim3(32, 32, 4), 256, 0, stream>>>(wq, wk, wv, wo, WqT, WkT, WvT, WoT);
  klw<<<16, 256, 0, stream>>>(wts, lwbuf);
  kgemm_qkv<<<dim3(8, 32, 3), 256, 0, stream>>>(Xq, Xk, Xv, WqT, WkT, WvT, bq, bk, bv, Qb, Kb, Vb);
  kattn<<<dim3(16, 32), 256, 0, stream>>>(Qb, Kb, Vb, lwbuf, AO);
  kgemm_o<<<dim3(8, 32), 256, 0, stream>>>(AO, WoT, bo, out);
}

// Round 2
// 174.878 us; speedup vs baseline: 1.4011x; 1.4011x over previous
//
#include <hip/hip_runtime.h>

typedef unsigned short u16;
typedef __bf16 bf16x8 __attribute__((ext_vector_type(8)));
typedef float f32x4 __attribute__((ext_vector_type(4)));

#define D_MODEL 1024
#define NH 16
#define DKD 64
#define BB 2
#define SS 2048
#define LDSK 72   // padded LDS row stride (u16) = 36 words: bank-balanced, 16B-aligned rows

__device__ __forceinline__ u16 f2bf(float f) {
  union { float f; unsigned u; } x; x.f = f;
  unsigned r = x.u + 0x7fffu + ((x.u >> 16) & 1u);
  return (u16)(r >> 16);
}

__device__ __forceinline__ void gld16(const u16* g, u16* l) {
  __builtin_amdgcn_global_load_lds((__attribute__((address_space(1))) void*)(g),
                                   (__attribute__((address_space(3))) void*)(l),
                                   16, 0, 0);
}

// ---------------- prep: fp32 -> bf16 activation convert ----------------
extern "C" __global__ void __launch_bounds__(256) kprep_conv(
    const float* __restrict__ q, const float* __restrict__ k, const float* __restrict__ v,
    u16* __restrict__ xq, u16* __restrict__ xk, u16* __restrict__ xv)
{
  int z = blockIdx.y;
  const float* s = z == 0 ? q : (z == 1 ? k : v);
  u16* d = z == 0 ? xq : (z == 1 ? xk : xv);
  int i = (blockIdx.x * 256 + threadIdx.x) * 4;
  float4 val = *(const float4*)(s + i);
  ushort4 o;
  o.x = f2bf(val.x); o.y = f2bf(val.y); o.z = f2bf(val.z); o.w = f2bf(val.w);
  *(ushort4*)(d + i) = o;
}

// ---------------- prep: weight transpose + bf16 convert ----------------
extern "C" __global__ void __launch_bounds__(256) kprep_wt(
    const float* __restrict__ w0, const float* __restrict__ w1,
    const float* __restrict__ w2, const float* __restrict__ w3,
    u16* __restrict__ o0, u16* __restrict__ o1, u16* __restrict__ o2, u16* __restrict__ o3)
{
  const float* src; u16* dst;
  switch (blockIdx.z) {
    case 0: src = w0; dst = o0; break;
    case 1: src = w1; dst = o1; break;
    case 2: src = w2; dst = o2; break;
    default: src = w3; dst = o3; break;
  }
  __shared__ float t[32][33];
  int n0 = blockIdx.x * 32, k0 = blockIdx.y * 32;
  int tx = threadIdx.x & 31, ty = threadIdx.x >> 5;
  #pragma unroll
  for (int i = 0; i < 32; i += 8)
    t[ty + i][tx] = src[(k0 + ty + i) * D_MODEL + n0 + tx];
  __syncthreads();
  #pragma unroll
  for (int i = 0; i < 32; i += 8)
    dst[(size_t)(n0 + ty + i) * D_MODEL + k0 + tx] = f2bf(t[tx][ty + i]);
}

// ---------------- prep: log2(weights + 1e-20) ----------------
extern "C" __global__ void __launch_bounds__(256) klw(
    const float* __restrict__ w, float* __restrict__ lw)
{
  int i = blockIdx.x * 256 + threadIdx.x;
  if (i < BB * SS) lw[i] = log2f(w[i] + 1e-20f);
}

// ---------------- shared GEMM core: C(128x128) = A(128xK) * Bt(128xK)^T ----------------
__device__ __forceinline__ void gemm_tile(const u16* __restrict__ Ag, const u16* __restrict__ Bg,
                                          u16* As, u16* Bs, f32x4 acc[4][4], int tid)
{
  int lane = tid & 63;
  int lr = lane & 15, lg = lane >> 4;
  int w = tid >> 6, wr = w >> 1, wc = w & 1;
  for (int k0 = 0; k0 < D_MODEL; k0 += 32) {
    #pragma unroll
    for (int c = 0; c < 2; ++c) {
      int idx = tid + c * 256;
      int row = idx >> 2, col = (idx & 3) * 8;
      gld16(Ag + row * D_MODEL + k0 + col, As + idx * 8);
      gld16(Bg + row * D_MODEL + k0 + col, Bs + idx * 8);
    }
    __syncthreads();
    bf16x8 af[4], bfr[4];
    #pragma unroll
    for (int mi = 0; mi < 4; ++mi)
      af[mi] = *(const bf16x8*)(As + (wr * 64 + mi * 16 + lr) * 32 + lg * 8);
    #pragma unroll
    for (int nj = 0; nj < 4; ++nj)
      bfr[nj] = *(const bf16x8*)(Bs + (wc * 64 + nj * 16 + lr) * 32 + lg * 8);
    #pragma unroll
    for (int mi = 0; mi < 4; ++mi)
      #pragma unroll
      for (int nj = 0; nj < 4; ++nj)
        acc[mi][nj] = __builtin_amdgcn_mfma_f32_16x16x32_bf16(af[mi], bfr[nj], acc[mi][nj], 0, 0, 0);
    __syncthreads();
  }
}

// ---------------- fused QKV projection ----------------
extern "C" __global__ void __launch_bounds__(256) kgemm_qkv(
    const u16* __restrict__ xq, const u16* __restrict__ xk, const u16* __restrict__ xv,
    const u16* __restrict__ wqt, const u16* __restrict__ wkt, const u16* __restrict__ wvt,
    const float* __restrict__ bq, const float* __restrict__ bk, const float* __restrict__ bv,
    u16* __restrict__ Qb, u16* __restrict__ Kb, u16* __restrict__ Vb)
{
  __shared__ u16 As[128 * 32], Bs[128 * 32];
  int z = blockIdx.z;
  const u16* X  = z == 0 ? xq : (z == 1 ? xk : xv);
  const u16* Wt = z == 0 ? wqt : (z == 1 ? wkt : wvt);
  const float* bias = z == 0 ? bq : (z == 1 ? bk : bv);
  u16* dst = z == 0 ? Qb : (z == 1 ? Kb : Vb);
  int tid = threadIdx.x;
  f32x4 zero = {0.f, 0.f, 0.f, 0.f};
  f32x4 acc[4][4];
  #pragma unroll
  for (int i = 0; i < 4; ++i)
    #pragma unroll
    for (int j = 0; j < 4; ++j) acc[i][j] = zero;
  int m0 = blockIdx.y * 128, n0 = blockIdx.x * 128;
  gemm_tile(X + (size_t)m0 * D_MODEL, Wt + (size_t)n0 * D_MODEL, As, Bs, acc, tid);
  int lane = tid & 63, lr = lane & 15, lg = lane >> 4;
  int w = tid >> 6, wr = w >> 1, wc = w & 1;
  #pragma unroll
  for (int mi = 0; mi < 4; ++mi)
    #pragma unroll
    for (int nj = 0; nj < 4; ++nj) {
      int n = n0 + wc * 64 + nj * 16 + lr;
      float bs = bias[n];
      int h = n >> 6, dk = n & 63;
      #pragma unroll
      for (int j = 0; j < 4; ++j) {
        int m = m0 + wr * 64 + mi * 16 + lg * 4 + j;
        int b = m >> 11, s = m & 2047;
        dst[(((size_t)(b * NH + h)) * SS + s) * DKD + dk] = f2bf(acc[mi][nj][j] + bs);
      }
    }
}

// ---------------- output projection ----------------
extern "C" __global__ void __launch_bounds__(256) kgemm_o(
    const u16* __restrict__ AO, const u16* __restrict__ wot,
    const float* __restrict__ bo, float* __restrict__ out)
{
  __shared__ u16 As[128 * 32], Bs[128 * 32];
  int tid = threadIdx.x;
  f32x4 zero = {0.f, 0.f, 0.f, 0.f};
  f32x4 acc[4][4];
  #pragma unroll
  for (int i = 0; i < 4; ++i)
    #pragma unroll
    for (int j = 0; j < 4; ++j) acc[i][j] = zero;
  int m0 = blockIdx.y * 128, n0 = blockIdx.x * 128;
  gemm_tile(AO + (size_t)m0 * D_MODEL, wot + (size_t)n0 * D_MODEL, As, Bs, acc, tid);
  int lane = tid & 63, lr = lane & 15, lg = lane >> 4;
  int w = tid >> 6, wr = w >> 1, wc = w & 1;
  #pragma unroll
  for (int mi = 0; mi < 4; ++mi)
    #pragma unroll
    for (int nj = 0; nj < 4; ++nj) {
      int n = n0 + wc * 64 + nj * 16 + lr;
      float bs = bo[n];
      #pragma unroll
      for (int j = 0; j < 4; ++j) {
        int m = m0 + wr * 64 + mi * 16 + lg * 4 + j;
        out[(size_t)m * D_MODEL + n] = acc[mi][nj][j] + bs;
      }
    }
}

// ---------------- flash attention, swapped-QK^T in-register softmax ----------------
// Q,K,V: (B,H,S,64) bf16. lw2: (B,S) f32 (log2 domain). AO: (B,S,1024) bf16.
// Per block: 64 q rows (4 waves x 16). Per wave: St = K*Q^T (kv rows, q cols),
// softmax lane-local over kv, O^T = V^T * P^T so O columns = q = lane&15.
extern "C" __global__ void __launch_bounds__(256) kattn(
    const u16* __restrict__ Qb, const u16* __restrict__ Kb, const u16* __restrict__ Vb,
    const float* __restrict__ lw2, u16* __restrict__ AO)
{
  __shared__ __align__(16) u16 Ks[64 * LDSK];
  __shared__ __align__(16) u16 Vt[64 * LDSK];
  __shared__ __align__(16) unsigned Pt[4][16 * 36];  // per-wave private: [q=16][kv-pair words, stride 36]

  int tid = threadIdx.x, lane = tid & 63, w = tid >> 6;
  int lr = lane & 15, lg = lane >> 4;
  int bh = blockIdx.y, b = bh >> 4, h = bh & 15;
  int q0 = blockIdx.x * 64;

  const u16* Qg = Qb + ((size_t)bh * SS + q0 + w * 16) * DKD;
  const u16* Kg = Kb + (size_t)bh * SS * DKD;
  const u16* Vg = Vb + (size_t)bh * SS * DKD;
  const float* lwb = lw2 + b * SS;

  // Q as B-fragment: col = q = lr, k = lg*8 + idx (per 32-chunk ki)
  bf16x8 qf[2];
  qf[0] = *(const bf16x8*)(Qg + lr * DKD + lg * 8);
  qf[1] = *(const bf16x8*)(Qg + lr * DKD + 32 + lg * 8);

  f32x4 zero = {0.f, 0.f, 0.f, 0.f};
  float m2 = -1e30f, lsum = 0.f;
  f32x4 acco[4] = {zero, zero, zero, zero};   // O^T[dk = dn*16+lg*4+j][q = lr]

  int i0 = tid, i1 = tid + 256;
  bf16x8 kpre[2];
  u16 vpre[16];

#define LOADK(kvn) do { \
    kpre[0] = *(const bf16x8*)(Kg + (size_t)((kvn) + (i0 >> 3)) * DKD + (i0 & 7) * 8); \
    kpre[1] = *(const bf16x8*)(Kg + (size_t)((kvn) + (i1 >> 3)) * DKD + (i1 & 7) * 8); \
  } while (0)
#define LOADV(kvn) do { \
    _Pragma("unroll") \
    for (int g = 0; g < 2; ++g) \
      _Pragma("unroll") \
      for (int j = 0; j < 8; ++j) \
        vpre[g * 8 + j] = Vg[(size_t)((kvn) + (w * 2 + g) * 8 + j) * DKD + lane]; \
  } while (0)
#define WRITEKV() do { \
    *(bf16x8*)&Ks[(i0 >> 3) * LDSK + (i0 & 7) * 8] = kpre[0]; \
    *(bf16x8*)&Ks[(i1 >> 3) * LDSK + (i1 & 7) * 8] = kpre[1]; \
    _Pragma("unroll") \
    for (int g = 0; g < 2; ++g) { \
      union { bf16x8 v; u16 s[8]; } tv; \
      _Pragma("unroll") \
      for (int j = 0; j < 8; ++j) tv.s[j] = vpre[g * 8 + j]; \
      *(bf16x8*)&Vt[lane * LDSK + (w * 2 + g) * 8] = tv.v; \
    } \
  } while (0)

  // prologue: stage tile 0
  LOADK(0); LOADV(0);
  WRITEKV();
  __syncthreads();

  for (int kv0 = 0; kv0 < SS; kv0 += 64) {
    bool more = (kv0 + 64 < SS);
    if (more) { LOADK(kv0 + 64); LOADV(kv0 + 64); }  // issue early; latency hides under compute

    // ---- St = K * Q^T : St[kv = nk*16 + lg*4 + j][q = lr] ----
    f32x4 st[4] = {zero, zero, zero, zero};
    #pragma unroll
    for (int ki = 0; ki < 2; ++ki) {
      bf16x8 kf[4];
      #pragma unroll
      for (int nk = 0; nk < 4; ++nk)
        kf[nk] = *(const bf16x8*)&Ks[(nk * 16 + lr) * LDSK + ki * 32 + lg * 8];
      #pragma unroll
      for (int nk = 0; nk < 4; ++nk)
        st[nk] = __builtin_amdgcn_mfma_f32_16x16x32_bf16(kf[nk], qf[ki], st[nk], 0, 0, 0);
    }

    // ---- scores in log2 domain: sc2 = st * (0.125*log2e) + log2(w) ----
    float4 lwv[4];
    #pragma unroll
    for (int nk = 0; nk < 4; ++nk)
      lwv[nk] = *(const float4*)(lwb + kv0 + nk * 16 + lg * 4);
    float sc2[4][4];
    #pragma unroll
    for (int nk = 0; nk < 4; ++nk) {
      sc2[nk][0] = fmaf(st[nk][0], 0.18033688f, lwv[nk].x);
      sc2[nk][1] = fmaf(st[nk][1], 0.18033688f, lwv[nk].y);
      sc2[nk][2] = fmaf(st[nk][2], 0.18033688f, lwv[nk].z);
      sc2[nk][3] = fmaf(st[nk][3], 0.18033688f, lwv[nk].w);
    }

    // ---- in-lane max over 16, then 2 shfls over lg ----
    float mx = sc2[0][0];
    #pragma unroll
    for (int nk = 0; nk < 4; ++nk)
      #pragma unroll
      for (int j = 0; j < 4; ++j) mx = fmaxf(mx, sc2[nk][j]);
    mx = fmaxf(mx, __shfl_xor(mx, 16));
    mx = fmaxf(mx, __shfl_xor(mx, 32));
    float mnew = fmaxf(m2, mx);
    float scal = exp2f(m2 - mnew);

    // ---- exp + sum ----
    float p[4][4], ps = 0.f;
    #pragma unroll
    for (int nk = 0; nk < 4; ++nk)
      #pragma unroll
      for (int j = 0; j < 4; ++j) {
        p[nk][j] = exp2f(sc2[nk][j] - mnew);
        ps += p[nk][j];
      }
    ps += __shfl_xor(ps, 16);
    ps += __shfl_xor(ps, 32);
    lsum = lsum * scal + ps;
    m2 = mnew;
    #pragma unroll
    for (int dn = 0; dn < 4; ++dn) acco[dn] *= scal;

    // ---- P^T redistribution via wave-private LDS (pairs packed to u32) ----
    #pragma unroll
    for (int nk = 0; nk < 4; ++nk) {
      union { unsigned u; __bf16 b2[2]; } c0, c1;
      c0.b2[0] = (__bf16)p[nk][0]; c0.b2[1] = (__bf16)p[nk][1];
      c1.b2[0] = (__bf16)p[nk][2]; c1.b2[1] = (__bf16)p[nk][3];
      *(uint2*)&Pt[w][lr * 36 + nk * 8 + lg * 2] = make_uint2(c0.u, c1.u);
    }
    // ---- O^T += V^T * P^T (same-wave LDS ordering; no barrier needed) ----
    #pragma unroll
    for (int ks = 0; ks < 2; ++ks) {
      bf16x8 F = *(const bf16x8*)&Pt[w][lr * 36 + ks * 16 + lg * 4];
      #pragma unroll
      for (int dn = 0; dn < 4; ++dn) {
        bf16x8 vf = *(const bf16x8*)&Vt[(dn * 16 + lr) * LDSK + ks * 32 + lg * 8];
        acco[dn] = __builtin_amdgcn_mfma_f32_16x16x32_bf16(vf, F, acco[dn], 0, 0, 0);
      }
    }

    if (more) {
      __syncthreads();   // all waves done reading Ks/Vt
      WRITEKV();
      __syncthreads();   // next tile staged
    }
  }

  // ---- epilogue: O[q][dk] = O^T / lsum ----
  float inv = 1.0f / lsum;
  int s = q0 + w * 16 + lr;
  size_t base = ((size_t)b * SS + s) * D_MODEL + h * DKD;
  #pragma unroll
  for (int dn = 0; dn < 4; ++dn) {
    ushort4 o;
    o.x = f2bf(acco[dn][0] * inv);
    o.y = f2bf(acco[dn][1] * inv);
    o.z = f2bf(acco[dn][2] * inv);
    o.w = f2bf(acco[dn][3] * inv);
    *(ushort4*)(AO + base + dn * 16 + lg * 4) = o;
  }
#undef LOADK
#undef LOADV
#undef WRITEKV
}

extern "C" void kernel_launch(void* const* d_in, const int* in_sizes, int n_in,
                              void* d_out, int out_size, void* d_ws, size_t ws_size,
                              hipStream_t stream) {
  const float* query = (const float*)d_in[0];
  const float* key_  = (const float*)d_in[1];
  const float* value = (const float*)d_in[2];
  const float* wts   = (const float*)d_in[3];
  const float* wq = (const float*)d_in[4];
  const float* bq = (const float*)d_in[5];
  const float* wk = (const float*)d_in[6];
  const float* bk = (const float*)d_in[7];
  const float* wv = (const float*)d_in[8];
  const float* bv = (const float*)d_in[9];
  const float* wo = (const float*)d_in[10];
  const float* bo = (const float*)d_in[11];
  float* out = (float*)d_out;

  char* ws = (char*)d_ws;
  const size_t MB = 1024 * 1024;
  u16* Xq  = (u16*)(ws + 0 * MB);
  u16* Xk  = (u16*)(ws + 8 * MB);
  u16* Xv  = (u16*)(ws + 16 * MB);
  u16* WqT = (u16*)(ws + 24 * MB);
  u16* WkT = (u16*)(ws + 26 * MB);
  u16* WvT = (u16*)(ws + 28 * MB);
  u16* WoT = (u16*)(ws + 30 * MB);
  u16* Qb  = (u16*)(ws + 32 * MB);
  u16* Kb  = (u16*)(ws + 40 * MB);
  u16* Vb  = (u16*)(ws + 48 * MB);
  u16* AO  = (u16*)(ws + 56 * MB);
  float* lwbuf = (float*)(ws + 64 * MB);

  kprep_conv<<<dim3(4096, 3), 256, 0, stream>>>(query, key_, value, Xq, Xk, Xv);
  kprep_wt<<<dim3(32, 32, 4), 256, 0, stream>>>(wq, wk, wv, wo, WqT, WkT, WvT, WoT);
  klw<<<16, 256, 0, stream>>>(wts, lwbuf);
  kgemm_qkv<<<dim3(8, 32, 3), 256, 0, stream>>>(Xq, Xk, Xv, WqT, WkT, WvT, bq, bk, bv, Qb, Kb, Vb);
  kattn<<<dim3(32, 32), 256, 0, stream>>>(Qb, Kb, Vb, lwbuf, AO);
  kgemm_o<<<dim3(8, 32), 256, 0, stream>>>(AO, WoT, bo, out);
}